// Round 6
// baseline (214.223 us; speedup 1.0000x reference)
//
#include <hip/hip_runtime.h>
#include <hip/hip_bf16.h>
#include <math.h>

#define BT   8192   // B*T
#define DD   256    // D
#define EE   16     // E
#define NN   8192   // N codebook entries (C == 1)

typedef __attribute__((ext_vector_type(8))) short short8;   // bf16x8 MFMA frag
typedef __attribute__((ext_vector_type(4))) float f32x4;    // MFMA accumulator

__device__ __forceinline__ unsigned short f2bf(float x) {
  union { float f; unsigned int u; } c; c.f = x;
  unsigned int r = (c.u + 0x7FFFu + ((c.u >> 16) & 1u)) >> 16;   // RNE
  return (unsigned short)r;
}
__device__ __forceinline__ unsigned int ordf(float d) {
  union { float f; unsigned int u; } c; c.f = d;
  return ((int)c.u < 0) ? ~c.u : (c.u | 0x80000000u);
}
__device__ __forceinline__ unsigned long long shflxor64(unsigned long long v, int m) {
  unsigned int lo = (unsigned int)v, hi = (unsigned int)(v >> 32);
  lo = __shfl_xor((int)lo, m);
  hi = __shfl_xor((int)hi, m);
  return ((unsigned long long)hi << 32) | lo;
}
__device__ __forceinline__ void gload_lds16(const void* g, void* l) {
  __builtin_amdgcn_global_load_lds((const __attribute__((address_space(1))) void*)g,
                                   (__attribute__((address_space(3))) void*)l, 16, 0, 0);
}

// ---------------- k_pre: fused Wt-transpose + embT + LN/proj/xmb ------------
// blocks [0,512):    W[d][n] fp32 -> Wt[n][d] bf16 (LDS-tiled, coalesced writes)
// blocks [512,544):  emb -> embT bf16 + sqe + keys init (+done zero)
// blocks [544,800):  xmb bf16 cast, LayerNorm, projb bf16, sumexp zero
#define XT_LD 65   // float4 row stride (64 + 1 pad -> conflict-free)
__global__ __launch_bounds__(256) void k_pre(const float* __restrict__ xs,
                                             const int* __restrict__ mm,
                                             const float* __restrict__ memb,
                                             const float* __restrict__ gamma,
                                             const float* __restrict__ beta,
                                             const float* __restrict__ P,
                                             const float* __restrict__ W,
                                             const float* __restrict__ emb,
                                             unsigned short* __restrict__ xmb,
                                             unsigned short* __restrict__ projb,
                                             unsigned short* __restrict__ Wt,
                                             unsigned short* __restrict__ embT,
                                             float* __restrict__ sqe,
                                             unsigned long long* __restrict__ keys,
                                             float* __restrict__ sumexp,
                                             unsigned int* __restrict__ done) {
  __shared__ __align__(16) float xt[32 * XT_LD * 4];   // 33 KB shared scratch
  __shared__ float stats[32][2];
  int bid = blockIdx.x;
  int tid = threadIdx.x;

  if (bid < 512) {             // ---- Wt transpose: 64n x 64d tile ----
    int n0 = (bid & 127) * 64;
    int d0 = (bid >> 7) * 64;
    #pragma unroll
    for (int pass = 0; pass < 16; pass++) {
      int idx = pass * 256 + tid;
      int dd = idx >> 6, ln = idx & 63;
      xt[ln * 65 + dd] = W[(size_t)(d0 + dd) * NN + n0 + ln];
    }
    __syncthreads();
    #pragma unroll
    for (int pass = 0; pass < 2; pass++) {
      int g = pass * 256 + tid;
      int row = g >> 3, c8 = g & 7;
      short8 v;
      #pragma unroll
      for (int i = 0; i < 8; i++) v[i] = (short)f2bf(xt[row * 65 + c8 * 8 + i]);
      *(short8*)(Wt + (size_t)(n0 + row) * DD + d0 + c8 * 8) = v;
    }
    return;
  }
  if (bid < 544) {             // ---- embT + sqe + keys ----
    if (bid == 512 && tid == 0) *done = 0u;
    int n = (bid - 512) * 256 + tid;
    float e[EE];
    float sq = 0.f;
    #pragma unroll
    for (int k = 0; k < EE; k++) { e[k] = emb[k * NN + n]; sq += e[k] * e[k]; }
    short8 lo, hi;
    #pragma unroll
    for (int k = 0; k < 8; k++) { lo[k] = (short)f2bf(e[k]); hi[k] = (short)f2bf(e[k + 8]); }
    *(short8*)(embT + (size_t)n * EE)     = lo;
    *(short8*)(embT + (size_t)n * EE + 8) = hi;
    sqe[n] = sq;
    keys[n] = ~0ULL;
    return;
  }
  // ---- LN + projection + xmb ----
  int pb = bid - 544;
  int t0 = pb * 32;
  int w = tid >> 6;
  int col4 = tid & 63;
  float4 mb4 = ((const float4*)memb)[col4];

  #pragma unroll
  for (int j = 0; j < 8; j++) {
    int k = tid + j * 256;
    int row = w + j * 4;
    float4 xv = ((const float4*)xs)[(size_t)pb * 2048 + k];
    int m = mm[t0 + row];
    float4 v = m ? mb4 : xv;
    ushort2 o01 = { f2bf(v.x), f2bf(v.y) };
    ushort2 o23 = { f2bf(v.z), f2bf(v.w) };
    ((ushort2*)(xmb + (size_t)(t0 + row) * DD + col4 * 4))[0] = o01;
    ((ushort2*)(xmb + (size_t)(t0 + row) * DD + col4 * 4))[1] = o23;
    *(float4*)&xt[(row * XT_LD + col4) * 4] = xv;
  }
  __syncthreads();
  {
    int t = tid >> 3, g = tid & 7;
    float s = 0.f, s2 = 0.f;
    #pragma unroll
    for (int i = 0; i < 8; i++) {
      float4 v = *(const float4*)&xt[(t * XT_LD + g * 8 + i) * 4];
      s  += v.x + v.y + v.z + v.w;
      s2 += v.x * v.x + v.y * v.y + v.z * v.z + v.w * v.w;
    }
    #pragma unroll
    for (int m = 1; m <= 4; m <<= 1) { s += __shfl_xor(s, m); s2 += __shfl_xor(s2, m); }
    if (g == 0) {
      float mu = s * (1.0f / DD);
      float var = s2 * (1.0f / DD) - mu * mu;
      stats[t][0] = mu;
      stats[t][1] = rsqrtf(var + 1e-5f);
    }
  }
  if (tid < 32) sumexp[t0 + tid] = 0.f;
  __syncthreads();
  {
    int t = tid >> 3, e0 = (tid & 7) * 2;
    float mu = stats[t][0], rstd = stats[t][1];
    float a0 = 0.f, a1 = 0.f;
    for (int d = 0; d < DD; d += 4) {
      float4 xv = *(const float4*)&xt[(t * XT_LD + (d >> 2)) * 4];
      float xd[4] = { xv.x, xv.y, xv.z, xv.w };
      #pragma unroll
      for (int dd = 0; dd < 4; dd++) {
        float h = (xd[dd] - mu) * rstd * gamma[d + dd] + beta[d + dd];
        a0 += h * P[(d + dd) * EE + e0];
        a1 += h * P[(d + dd) * EE + e0 + 1];
      }
    }
    ushort2 o = { f2bf(a0), f2bf(a1) };
    *(ushort2*)(projb + (size_t)(t0 + t) * EE + e0) = o;
  }
}

// ------- k_argmin: MFMA dist + packed-key argmin ----------------------------
#define NS4 8
#define ASEG (NN / NS4)   // 1024 n per block
__global__ __launch_bounds__(256) void k_argmin(const unsigned short* __restrict__ projb,
                                                const unsigned short* __restrict__ embT,
                                                const float* __restrict__ sqe,
                                                unsigned long long* __restrict__ keys) {
  int tid = threadIdx.x;
  int w = tid >> 6, lane = tid & 63;
  int q = lane >> 4, c = lane & 15;
  int tw = blockIdx.x * 64 + w * 16;
  int nseg = blockIdx.y * ASEG;

  short8 a = {0, 0, 0, 0, 0, 0, 0, 0};
  if (q < 2) a = *(const short8*)(projb + (size_t)(tw + c) * EE + q * 8);

  unsigned long long bk[4];
  #pragma unroll
  for (int r = 0; r < 4; r++) bk[r] = ~0ULL;

  #pragma unroll 2
  for (int it = 0; it < ASEG / 16; it++) {
    int n = nseg + it * 16 + c;
    short8 b = {0, 0, 0, 0, 0, 0, 0, 0};
    if (q < 2) b = *(const short8*)(embT + (size_t)n * EE + q * 8);
    float sq = sqe[n];
    f32x4 acc = (f32x4){0.f, 0.f, 0.f, 0.f};
    acc = __builtin_amdgcn_mfma_f32_16x16x32_bf16(a, b, acc, 0, 0, 0);
    #pragma unroll
    for (int r = 0; r < 4; r++) {
      float dist = sq - 2.f * acc[r];
      unsigned long long key = ((unsigned long long)ordf(dist) << 32) | (unsigned int)n;
      bk[r] = key < bk[r] ? key : bk[r];
    }
  }
  #pragma unroll
  for (int r = 0; r < 4; r++) {
    #pragma unroll
    for (int m = 1; m <= 8; m <<= 1) {
      unsigned long long o = shflxor64(bk[r], m);
      bk[r] = o < bk[r] ? o : bk[r];
    }
  }
  if (c == 0) {
    #pragma unroll
    for (int r = 0; r < 4; r++)
      atomicMin(&keys[tw + q * 4 + r], bk[r]);
  }
}

// ------- k_ce6: A-in-registers wide-short GEMM, B double-buffered -----------
// grid (32, 8); block 512 = 8 waves (4m x 2n); block tile 256m x 1024n.
// A (64 rows x K=256 per wave) lives in VGPRs for the whole kernel
// (__launch_bounds__(512,2) -> 256-VGPR budget). Loop over n in 64-chunks:
// stage B chunk (32 KB, full K) into dbuf LDS via global_load_lds while
// computing the previous chunk. B LDS uses the R5-verified conflict-free
// xor-quarter swizzle. Fused epilogue: exp-sum + target capture; last block
// (done-counter) computes the final masked mean.
#define CE_NSPLIT 8
#define CE_NCHUNK 64
#define CE_ITERS ((NN / CE_NSPLIT) / CE_NCHUNK)   // 16
__global__ __launch_bounds__(512, 2) void k_ce6(const unsigned short* __restrict__ xmb,
                                                const unsigned short* __restrict__ Wt,
                                                const unsigned long long* __restrict__ keys,
                                                const int* __restrict__ padm,
                                                const int* __restrict__ mm,
                                                float* __restrict__ sumexp,
                                                float* __restrict__ ltar,
                                                unsigned int* __restrict__ done,
                                                float* __restrict__ out) {
  __shared__ __align__(16) unsigned short ldsB[2 * 16384];   // 64 KB (2 x 64n x 256K)
  int tid = threadIdx.x;
  int w = tid >> 6, lane = tid & 63;
  int q = lane >> 4, c = lane & 15;
  int wm = w >> 1, wn = w & 1;
  int t0 = blockIdx.x * 256;
  int nb0 = blockIdx.y * (NN / CE_NSPLIT);
  int sw = q ^ ((c >> 1) & 3);      // physical quarter slot for logical q

  // ---- stage chunk 0 (async) ----
  #pragma unroll
  for (int p = 0; p < 4; p++) {
    int g = p * 512 + tid;                 // 16B slot, linear in LDS
    int kc = g >> 8, g2 = g & 255;
    int row = g2 >> 2;
    int qg = (g2 & 3) ^ ((g2 >> 3) & 3);   // stored quarter (xor swizzle)
    gload_lds16(Wt + (size_t)(nb0 + row) * DD + kc * 32 + qg * 8, ldsB + g * 8);
  }

  // ---- A fragments: 64 rows x K=256 per wave, resident all kernel ----
  short8 a[4][8];
  #pragma unroll
  for (int mi = 0; mi < 4; mi++)
    #pragma unroll
    for (int ks = 0; ks < 8; ks++)
      a[mi][ks] = *(const short8*)(xmb + (size_t)(t0 + wm * 64 + mi * 16 + c) * DD + ks * 32 + q * 8);

  int tg[4][4];
  #pragma unroll
  for (int mi = 0; mi < 4; mi++)
    #pragma unroll
    for (int r = 0; r < 4; r++)
      tg[mi][r] = (int)(unsigned int)(keys[t0 + wm * 64 + mi * 16 + q * 4 + r] & 0xFFFFFFFFULL);

  float rs[4][4];
  #pragma unroll
  for (int mi = 0; mi < 4; mi++)
    #pragma unroll
    for (int r = 0; r < 4; r++) rs[mi][r] = 0.f;

  for (int it = 0; it < CE_ITERS; it++) {
    __syncthreads();   // chunk `it` staged; all waves done with other buffer
    if (it + 1 < CE_ITERS) {
      int nb = nb0 + (it + 1) * CE_NCHUNK;
      int bfn = (it + 1) & 1;
      #pragma unroll
      for (int p = 0; p < 4; p++) {
        int g = p * 512 + tid;
        int kc = g >> 8, g2 = g & 255;
        int row = g2 >> 2;
        int qg = (g2 & 3) ^ ((g2 >> 3) & 3);
        gload_lds16(Wt + (size_t)(nb + row) * DD + kc * 32 + qg * 8,
                    ldsB + bfn * 16384 + g * 8);
      }
    }
    const unsigned short* bp = ldsB + (it & 1) * 16384;

    f32x4 acc[4][2];
    #pragma unroll
    for (int mi = 0; mi < 4; mi++)
      #pragma unroll
      for (int ni = 0; ni < 2; ni++) acc[mi][ni] = (f32x4){0.f, 0.f, 0.f, 0.f};

    #pragma unroll
    for (int kc = 0; kc < 8; kc++) {
      short8 b[2];
      #pragma unroll
      for (int ni = 0; ni < 2; ni++)
        b[ni] = *(const short8*)(bp + kc * 2048 + (wn * 32 + ni * 16 + c) * 32 + sw * 8);
      #pragma unroll
      for (int mi = 0; mi < 4; mi++)
        #pragma unroll
        for (int ni = 0; ni < 2; ni++)
          acc[mi][ni] = __builtin_amdgcn_mfma_f32_16x16x32_bf16(a[mi][kc], b[ni], acc[mi][ni], 0, 0, 0);
    }

    int nbase = nb0 + it * CE_NCHUNK + wn * 32;
    #pragma unroll
    for (int mi = 0; mi < 4; mi++)
      #pragma unroll
      for (int ni = 0; ni < 2; ni++) {
        int col = nbase + ni * 16 + c;
        #pragma unroll
        for (int r = 0; r < 4; r++) {
          float v = acc[mi][ni][r];
          if (col == tg[mi][r])
            ltar[t0 + wm * 64 + mi * 16 + q * 4 + r] = v;   // unique writer grid-wide
          rs[mi][r] += __expf(v);
        }
      }
  }

  // reduce exp-sums over the 16 column lanes, one atomic per row per wave
  #pragma unroll
  for (int mi = 0; mi < 4; mi++)
    #pragma unroll
    for (int r = 0; r < 4; r++) {
      float s = rs[mi][r];
      s += __shfl_xor(s, 1);
      s += __shfl_xor(s, 2);
      s += __shfl_xor(s, 4);
      s += __shfl_xor(s, 8);
      if (c == 0)
        atomicAdd(&sumexp[t0 + wm * 64 + mi * 16 + q * 4 + r], s);
    }

  // ---- last block computes the final masked mean ----
  __threadfence();            // release: ltar stores + sumexp atomics visible
  __syncthreads();
  __shared__ unsigned int lastv;
  if (tid == 0) lastv = atomicAdd(done, 1u);
  __syncthreads();
  if (lastv == 255u) {        // 32*8 - 1
    __threadfence();          // acquire
    float sum = 0.f, cnt = 0.f;
    for (int t = tid; t < BT; t += 512) {
      float ce = __logf(sumexp[t]) - ltar[t];
      if (padm[t] && mm[t]) { sum += ce; cnt += 1.f; }
    }
    #pragma unroll
    for (int off = 32; off; off >>= 1) { sum += __shfl_down(sum, off); cnt += __shfl_down(cnt, off); }
    __shared__ float frs[8], frc[8];
    int wid = tid >> 6, ln = tid & 63;
    if (ln == 0) { frs[wid] = sum; frc[wid] = cnt; }
    __syncthreads();
    if (tid == 0) {
      float S = 0.f, Cn = 0.f;
      #pragma unroll
      for (int i = 0; i < 8; i++) { S += frs[i]; Cn += frc[i]; }
      out[0] = S / Cn;
    }
  }
}

extern "C" void kernel_launch(void* const* d_in, const int* in_sizes, int n_in,
                              void* d_out, int out_size, void* d_ws, size_t ws_size,
                              hipStream_t stream) {
  const float* xs    = (const float*)d_in[0];
  const int*   padm  = (const int*)d_in[1];
  const int*   mm    = (const int*)d_in[2];
  const float* gamma = (const float*)d_in[3];
  const float* beta  = (const float*)d_in[4];
  const float* P     = (const float*)d_in[5];
  const float* emb   = (const float*)d_in[6];
  const float* W     = (const float*)d_in[7];
  const float* memb  = (const float*)d_in[8];
  float* out = (float*)d_out;

  char* ws = (char*)d_ws;
  size_t off = 0;
  unsigned short* xmb   = (unsigned short*)(ws + off); off += (size_t)BT * DD * 2;  // 4 MB
  unsigned short* Wtb   = (unsigned short*)(ws + off); off += (size_t)NN * DD * 2;  // 4 MB
  unsigned short* embT  = (unsigned short*)(ws + off); off += (size_t)NN * EE * 2;  // 256 KB
  unsigned short* projb = (unsigned short*)(ws + off); off += (size_t)BT * EE * 2;  // 256 KB
  float* sqe            = (float*)(ws + off);          off += (size_t)NN * 4;       // 32 KB
  unsigned long long* keys = (unsigned long long*)(ws + off); off += (size_t)BT * 8;// 64 KB
  float* sumexp         = (float*)(ws + off);          off += (size_t)BT * 4;       // 32 KB
  float* ltar           = (float*)(ws + off);          off += (size_t)BT * 4;       // 32 KB
  unsigned int* done    = (unsigned int*)(ws + off);   off += 64;

  k_pre   <<<800, 256, 0, stream>>>(xs, mm, memb, gamma, beta, P, W, emb,
                                    xmb, projb, Wtb, embT, sqe, keys, sumexp, done);
  k_argmin<<<dim3(BT / 64, NS4), 256, 0, stream>>>(projb, embT, sqe, keys);
  k_ce6   <<<dim3(32, CE_NSPLIT), 512, 0, stream>>>(xmb, Wtb, keys, padm, mm,
                                                    sumexp, ltar, done, out);
}